// Round 1
// baseline (1352.652 us; speedup 1.0000x reference)
//
#include <hip/hip_runtime.h>

// DMPNN encoder, algebraically reduced:
//   only layer i=2 matters (h not fed back);
//   cat @ Wi.T replaced by precomputed P[120,128] / Qb[6,128] table gathers.
// Cost floor: one streaming read of bond_n (1.074 GB) for col_w.

#define NN 16384   // nodes/edges
#define AA 16384   // bond_n rows
#define DD 128     // emb dim
#define LI 2       // last layer index — the only one that matters

#define SLABS 32
#define ROWS_PER_SLAB (AA / SLABS)   // 512

// ---------------- K1: prep — P/Qb tables + zero col_w & m ----------------
// grid 128 x 128 threads.
// blocks 0..119  : P[b,d]  = sum_k atom_emb[b,k] * Wi_w[2][d,k]        (k<128)
// blocks 120..125: Qb[b2,d]= Wi_b[2][d] + sum_k bond_emb[b2,k]*Wi_w[2][d,128+k]
// blocks 126..127: zero col_w[NN] and m[DD] (contiguous region of NN+DD floats)
__global__ __launch_bounds__(128) void k_prep(
    const float* __restrict__ atom_emb, const float* __restrict__ bond_emb,
    const float* __restrict__ Wi_w, const float* __restrict__ Wi_b,
    float* __restrict__ P, float* __restrict__ Qb, float* __restrict__ zero_region)
{
    __shared__ float e[DD];
    const int b = blockIdx.x, d = threadIdx.x;
    if (b < 120) {
        e[d] = atom_emb[b * DD + d];
        __syncthreads();
        const float* wr = Wi_w + LI * DD * 2 * DD + d * (2 * DD);
        float acc = 0.f;
        #pragma unroll 8
        for (int k = 0; k < DD; ++k) acc = fmaf(e[k], wr[k], acc);
        P[b * DD + d] = acc;
    } else if (b < 126) {
        const int b2 = b - 120;
        e[d] = bond_emb[b2 * DD + d];
        __syncthreads();
        const float* wr = Wi_w + LI * DD * 2 * DD + d * (2 * DD) + DD;
        float acc = Wi_b[LI * DD + d];
        #pragma unroll 8
        for (int k = 0; k < DD; ++k) acc = fmaf(e[k], wr[k], acc);
        Qb[b2 * DD + d] = acc;
    } else {
        for (int i = (b - 126) * DD + d; i < NN + DD; i += 2 * DD)
            zero_region[i] = 0.f;
    }
}

// ---------------- K2: col_w[n] = sum_a bond_n[a,n] ----------------
// The HBM-bound kernel: 1.074 GB streamed, float4-coalesced.
// grid (NN/1024, SLABS) = (16,32) = 512 blocks x 256 threads; 512 rows/slab.
__global__ __launch_bounds__(256) void k_colsum(
    const float* __restrict__ bond, float* __restrict__ col_w)
{
    const int c4 = blockIdx.x * 256 + threadIdx.x;        // float4 column index (0..4095)
    const size_t row_stride4 = NN / 4;
    const float4* p = reinterpret_cast<const float4*>(bond)
                    + (size_t)(blockIdx.y * ROWS_PER_SLAB) * row_stride4 + c4;
    float4 s = make_float4(0.f, 0.f, 0.f, 0.f);
    #pragma unroll 8
    for (int a = 0; a < ROWS_PER_SLAB; ++a) {
        float4 v = p[(size_t)a * row_stride4];
        s.x += v.x; s.y += v.y; s.z += v.z; s.w += v.w;
    }
    float* dst = col_w + c4 * 4;
    atomicAdd(dst + 0, s.x);
    atomicAdd(dst + 1, s.y);
    atomicAdd(dst + 2, s.z);
    atomicAdd(dst + 3, s.w);
}

// ---------------- K3: h_n = relu(P[x0]+P[x1]+Qb[e0]+Qb[e1]) -> d_out,
//                  fused partial m[d] += col_w[n]*h_n[n,d] ----------------
// grid 256 x 256 threads; block = 2 halves x 128 d; 64 rows/block.
__global__ __launch_bounds__(256) void k_hn(
    const int* __restrict__ x, const int* __restrict__ ea,
    const float* __restrict__ P, const float* __restrict__ Qb,
    const float* __restrict__ col_w,
    float* __restrict__ out, float* __restrict__ m)
{
    const int d    = threadIdx.x & (DD - 1);
    const int half = threadIdx.x >> 7;
    const int row0 = blockIdx.x * 64 + half * 32;
    float acc = 0.f;
    #pragma unroll 4
    for (int i = 0; i < 32; ++i) {
        const int n  = row0 + i;
        const int a0 = x[2 * n], a1 = x[2 * n + 1];
        const int b0 = ea[2 * n], b1 = ea[2 * n + 1];
        float v = P[a0 * DD + d] + P[a1 * DD + d]
                + Qb[b0 * DD + d] + Qb[b1 * DD + d];
        v = fmaxf(v, 0.f);
        out[(size_t)n * DD + d] = v;
        acc = fmaf(col_w[n], v, acc);
    }
    __shared__ float red[DD];
    if (half) red[d] = acc;
    __syncthreads();
    if (!half) atomicAdd(&m[d], acc + red[d]);
}

// ---------------- K4: mm = m @ Wm[2].T + Wm_b[2] (redundant per block),
//                  then out = relu(out + mm) in place ----------------
// grid 512 x 256; grid-stride float4; mm float4 is loop-invariant per thread.
__global__ __launch_bounds__(256) void k_final(
    const float* __restrict__ m, const float* __restrict__ Wm_w,
    const float* __restrict__ Wm_b, float* __restrict__ out)
{
    __shared__ float s_m[DD];
    __shared__ float s_mm[DD];
    const int tid = threadIdx.x;
    if (tid < DD) s_m[tid] = m[tid];
    __syncthreads();
    if (tid < DD) {
        const float* wr = Wm_w + LI * DD * DD + tid * DD;
        float acc = Wm_b[LI * DD + tid];
        #pragma unroll 8
        for (int k = 0; k < DD; ++k) acc = fmaf(s_m[k], wr[k], acc);
        s_mm[tid] = acc;
    }
    __syncthreads();

    float4* o4 = reinterpret_cast<float4*>(out);
    const int total = NN * DD / 4;                 // 524288
    int i = blockIdx.x * 256 + tid;
    // d0 = (4*i) & 127 is invariant under i += gridDim*256 (stride*4 % 128 == 0)
    const int d0 = (i * 4) & (DD - 1);
    const float4 mmv = *reinterpret_cast<const float4*>(&s_mm[d0]);
    for (; i < total; i += gridDim.x * 256) {
        float4 v = o4[i];
        v.x = fmaxf(v.x + mmv.x, 0.f);
        v.y = fmaxf(v.y + mmv.y, 0.f);
        v.z = fmaxf(v.z + mmv.z, 0.f);
        v.w = fmaxf(v.w + mmv.w, 0.f);
        o4[i] = v;
    }
}

extern "C" void kernel_launch(void* const* d_in, const int* in_sizes, int n_in,
                              void* d_out, int out_size, void* d_ws, size_t ws_size,
                              hipStream_t stream) {
    const int*   x        = (const int*)  d_in[0];   // [N,2] int32
    const int*   edge     = (const int*)  d_in[1];   // [N,2] int32
    const float* bond_n   = (const float*)d_in[2];   // [A,N] f32
    const float* atom_emb = (const float*)d_in[3];   // [120,128]
    const float* bond_emb = (const float*)d_in[4];   // [6,128]
    const float* Wi_w     = (const float*)d_in[5];   // [3,128,256]
    const float* Wi_b     = (const float*)d_in[6];   // [3,128]
    const float* Wm_w     = (const float*)d_in[7];   // [3,128,128]
    const float* Wm_b     = (const float*)d_in[8];   // [3,128]
    float* out = (float*)d_out;                      // [N,128] f32

    // ws layout (floats): col_w[NN] | m[DD] | P[120*DD] | Qb[6*DD]  (~131 KB)
    float* w     = (float*)d_ws;
    float* col_w = w;
    float* m     = w + NN;
    float* P     = w + NN + DD;
    float* Qb    = P + 120 * DD;

    k_prep<<<128, 128, 0, stream>>>(atom_emb, bond_emb, Wi_w, Wi_b, P, Qb, col_w);
    k_colsum<<<dim3(NN / 1024, SLABS), 256, 0, stream>>>(bond_n, col_w);
    k_hn<<<NN / 64, 256, 0, stream>>>(x, edge, P, Qb, col_w, out, m);
    k_final<<<512, 256, 0, stream>>>(m, Wm_w, Wm_b, out);
}